// Round 1
// 76.335 us; speedup vs baseline: 1.0275x; 1.0275x over previous
//
#include <hip/hip_runtime.h>

#define NB 8
#define LC 512
#define LQ 64
#define DD 256
#define NEG_BIG_F 1e30f

#define TPB 512            // 8 waves
#define NWAVE 8
#define RPW 2              // rows per wave  (NEW: one T-pass feeds 2 rows)
#define RPB (NWAVE * RPW)  // 16 rows per block
#define BPB (LC / RPB)     // 32 blocks per batch -> grid = 256 (1 block/CU)

// Broadcast a float from `lane` to all lanes as a wave-uniform (SGPR) value.
__device__ __forceinline__ float bcastf(float x, int lane) {
  return __uint_as_float((unsigned)__builtin_amdgcn_readlane((int)__float_as_uint(x), lane));
}

__global__ __launch_bounds__(TPB, 2) void rows_kernel(
    const float* __restrict__ context,   // [NB][LC][DD]
    const float* __restrict__ question,  // [NB][LQ][DD]
    const int*   __restrict__ mask,      // [NB][LQ]
    const float* __restrict__ att_w,     // [3*DD]
    const float* __restrict__ att_b,     // [1]
    const float* __restrict__ w_in,      // [DD]
    const float* __restrict__ w_mem,     // [DD]
    float4* __restrict__ ws4)            // [NB*LC] {rowmax, ctx1, U, 0}
{
  // T[c][j ^ (c&7)] = question[b][j][4c..4c+3].
  // Writes: lane=c (fixed j)  -> 8 distinct 16B slots per 128B phase.
  // Reads : lane=j (fixed c)  -> blockwise-XOR perm of consecutive float4s.
  // Both conflict-free.
  __shared__ float4 T[64][64];                   // 64 KiB
  __shared__ float sq_raw[LQ];                   // q-term of score (no bias/mask)
  __shared__ float q1_s[LQ];

  const int tid  = threadIdx.x;
  const int w    = tid >> 6;           // wave 0..7
  const int l    = tid & 63;           // lane
  const int b    = blockIdx.x / BPB;
  const int row0 = (blockIdx.x % BPB) * RPB;
  const int iA   = row0 + w * RPW;     // this wave's first context row
  const int iB   = iA + 1;             // second context row

  // ---- hoisted per-lane loads (lane = d-chunk) ----
  const float4 wc4 = ((const float4*)att_w)[l];
  const float4 wq4 = ((const float4*)(att_w + DD))[l];
  const float4 wp4 = ((const float4*)(att_w + 2 * DD))[l];
  const float4 wi4 = ((const float4*)w_in)[l];
  const float4 wm4 = ((const float4*)w_mem)[l];
  const float4 cA  = ((const float4*)(context + ((size_t)b * LC + iA) * DD))[l];
  const float4 cB  = ((const float4*)(context + ((size_t)b * LC + iB) * DD))[l];

  // ---- staging: instruction k loads ONE full q-row (row j = k*8 + w):
  // 64 lanes x 16B = exactly the 1KiB row -> perfectly coalesced.
  float4 v[8];
#pragma unroll
  for (int k = 0; k < 8; ++k)
    v[k] = ((const float4*)(question + ((size_t)b * LQ + (k * 8 + w)) * DD))[l];
#pragma unroll
  for (int k = 0; k < 8; ++k)
    T[l][(k * 8 + w) ^ (l & 7)] = v[k];

  // per-row partial dot products (lane l holds chunk l's contribution)
  float psq[8], pq1[8];
#pragma unroll
  for (int k = 0; k < 8; ++k) {
    psq[k] = v[k].x*wq4.x + v[k].y*wq4.y + v[k].z*wq4.z + v[k].w*wq4.w;
    pq1[k] = v[k].x*wm4.x + v[k].y*wm4.y + v[k].z*wm4.z + v[k].w*wm4.w;
  }
  // butterfly-reduce all 16 chains together (ILP hides shuffle latency)
#pragma unroll
  for (int off = 32; off > 0; off >>= 1) {
#pragma unroll
    for (int k = 0; k < 8; ++k) {
      psq[k] += __shfl_xor(psq[k], off);
      pq1[k] += __shfl_xor(pq1[k], off);
    }
  }
  if (l == 0) {
#pragma unroll
    for (int k = 0; k < 8; ++k) {
      sq_raw[k * 8 + w] = psq[k];
      q1_s[k * 8 + w]   = pq1[k];
    }
  }

  // ---- this wave's row-local terms (overlap with staging latency) ----
  float4 cpA, cpB;
  cpA.x = cA.x*wp4.x; cpA.y = cA.y*wp4.y; cpA.z = cA.z*wp4.z; cpA.w = cA.w*wp4.w;
  cpB.x = cB.x*wp4.x; cpB.y = cB.y*wp4.y; cpB.z = cB.z*wp4.z; cpB.w = cB.w*wp4.w;
  float scA = cA.x*wc4.x + cA.y*wc4.y + cA.z*wc4.z + cA.w*wc4.w;
  float scB = cB.x*wc4.x + cB.y*wc4.y + cB.z*wc4.z + cB.w*wc4.w;
  float c1A = cA.x*wi4.x + cA.y*wi4.y + cA.z*wi4.z + cA.w*wi4.w;
  float c1B = cB.x*wi4.x + cB.y*wi4.y + cB.z*wi4.z + cB.w*wi4.w;
#pragma unroll
  for (int off = 32; off > 0; off >>= 1) {
    scA += __shfl_xor(scA, off);
    scB += __shfl_xor(scB, off);
    c1A += __shfl_xor(c1A, off);
    c1B += __shfl_xor(c1B, off);
  }

  __syncthreads();

  // ---- main loop: lane l = q-column j; ctx chunk broadcast via readlane.
  // ONE pass over T feeds BOTH rows -> LDS read bytes per row halved.
  float a0 = 0.f, a1 = 0.f, a2 = 0.f, a3 = 0.f;   // row A chains
  float e0 = 0.f, e1 = 0.f, e2 = 0.f, e3 = 0.f;   // row B chains
#pragma unroll
  for (int c = 0; c < 64; ++c) {
    float4 qv = T[c][l ^ (c & 7)];
    a0 += bcastf(cpA.x, c) * qv.x;
    a1 += bcastf(cpA.y, c) * qv.y;
    a2 += bcastf(cpA.z, c) * qv.z;
    a3 += bcastf(cpA.w, c) * qv.w;
    e0 += bcastf(cpB.x, c) * qv.x;
    e1 += bcastf(cpB.y, c) * qv.y;
    e2 += bcastf(cpB.z, c) * qv.z;
    e3 += bcastf(cpB.w, c) * qv.w;
  }

  const float mf   = (float)mask[b * LQ + l];
  const float base = sq_raw[l] + att_b[0] - NEG_BIG_F * (1.0f - mf);
  float sA = (a0 + a1) + (a2 + a3) + scA + base;
  float sB = (e0 + e1) + (e2 + e3) + scB + base;
  const float q1_l = q1_s[l];

  float mA = sA, mB = sB;
#pragma unroll
  for (int off = 32; off > 0; off >>= 1) {
    mA = fmaxf(mA, __shfl_xor(mA, off));
    mB = fmaxf(mB, __shfl_xor(mB, off));
  }
  float pA = __expf(sA - mA);
  float pB = __expf(sB - mB);
  float psA = pA, puA = pA * q1_l;
  float psB = pB, puB = pB * q1_l;
#pragma unroll
  for (int off = 32; off > 0; off >>= 1) {
    psA += __shfl_xor(psA, off);
    puA += __shfl_xor(puA, off);
    psB += __shfl_xor(psB, off);
    puB += __shfl_xor(puB, off);
  }
  if (l == 0) {
    ws4[b * LC + iA] = make_float4(mA, c1A, puA / psA, 0.f);
    ws4[b * LC + iB] = make_float4(mB, c1B, puB / psB, 0.f);
  }
}

__global__ __launch_bounds__(512) void batch_kernel(
    const float4* __restrict__ ws4,
    float4* __restrict__ out4)           // [NB*LC] {c1, U, c1*U, U*H}
{
  const int b  = blockIdx.x;
  const int t  = threadIdx.x;           // row i
  const int gi = b * LC + t;
  const float4 v = ws4[gi];
  const float m = v.x, c1 = v.y, U = v.z;

  const int w = t >> 6, l = t & 63;
  __shared__ float rmax[8], rs[8], rc[8];

  float mx = m;
#pragma unroll
  for (int off = 32; off > 0; off >>= 1) mx = fmaxf(mx, __shfl_xor(mx, off));
  if (l == 0) rmax[w] = mx;
  __syncthreads();
  mx = rmax[0];
#pragma unroll
  for (int k = 1; k < 8; ++k) mx = fmaxf(mx, rmax[k]);

  float p  = __expf(m - mx);
  float ps = p;
  float pc = p * c1;
#pragma unroll
  for (int off = 32; off > 0; off >>= 1) {
    ps += __shfl_xor(ps, off);
    pc += __shfl_xor(pc, off);
  }
  if (l == 0) { rs[w] = ps; rc[w] = pc; }
  __syncthreads();
  float S = 0.f, C = 0.f;
#pragma unroll
  for (int k = 0; k < 8; ++k) { S += rs[k]; C += rc[k]; }

  const float H = C / S;
  out4[gi] = make_float4(c1, U, c1 * U, U * H);
}

extern "C" void kernel_launch(void* const* d_in, const int* in_sizes, int n_in,
                              void* d_out, int out_size, void* d_ws, size_t ws_size,
                              hipStream_t stream) {
  const float* context  = (const float*)d_in[0];
  const float* question = (const float*)d_in[1];
  const int*   mask     = (const int*)d_in[2];
  const float* att_w    = (const float*)d_in[3];
  const float* att_b    = (const float*)d_in[4];
  const float* w_in     = (const float*)d_in[5];
  const float* w_mem    = (const float*)d_in[6];
  float4* out4 = (float4*)d_out;
  float4* ws4  = (float4*)d_ws;

  rows_kernel<<<dim3(NB * BPB), dim3(TPB), 0, stream>>>(
      context, question, mask, att_w, att_b, w_in, w_mem, ws4);
  batch_kernel<<<dim3(NB), dim3(512), 0, stream>>>(ws4, out4);
}